// Round 9
// baseline (143.230 us; speedup 1.0000x reference)
//
#include <hip/hip_runtime.h>

#define FEATS 64
#define PSZ   64            // nodes per partition (= one gather block)
#define MAXP  1536          // 512 threads * 3 partitions >= 1172
#define PSCH  2344          // edges per chunk; 2344*512 >= 1.2M
#define SPT   512           // prep_scatter threads per block
#define PEPT  5             // ceil(PSCH/SPT)
#define NBMAX 512           // sort blocks = runs per partition
#define CAPP  2560          // padded LDS bucket capacity (mean ~1250, >30 sigma)

typedef __attribute__((ext_vector_type(8))) short short8;   // 8 bf16 = 4 VGPRs
typedef __attribute__((ext_vector_type(4))) float floatx4;  // MFMA accumulator

static __device__ __forceinline__ unsigned short f2bf(float f) {
    const unsigned int u = __float_as_uint(f);
    return (unsigned short)((u + 0x7FFFu + ((u >> 16) & 1u)) >> 16);
}
static __device__ __forceinline__ float bflo(unsigned int u) {
    return __uint_as_float(u << 16);            // low bf16 -> fp32
}
static __device__ __forceinline__ float bfhi(unsigned int u) {
    return __uint_as_float(u & 0xFFFF0000u);    // high bf16 -> fp32
}

// ---------------------------------------------------------------------------
// K1 prep_scatter (fused):
//  (A) Fs16 = bf16(feature * rsqrt(degree[row])) node-slice; block 0 also
//      writes the zero pad-row and WtB = W^T bf16.
//  (B) partition-sort of the block's PSCH-edge chunk in LDS. prk is 64-bit
//      (src|dl|p|r) so pass 2 reads NO global memory. Scan of the 1172
//      partition counts is hierarchical wave-shuffle: 3 barriers total
//      (vs ~20 for Hillis-Steele). ZERO global atomics.
// ---------------------------------------------------------------------------
__global__ __launch_bounds__(SPT) void prep_scatter(
        const float* __restrict__ degree,
        const float* __restrict__ feature,
        const float* __restrict__ Wm,
        const int* __restrict__ src,
        const int* __restrict__ dst,
        unsigned short* __restrict__ Fs16,
        unsigned short* __restrict__ WtB,
        int* __restrict__ slab,
        unsigned short* __restrict__ runoff,
        int n_nodes, int n_edges, int np, int rows_per) {
    __shared__ int cnt[MAXP];        // per-partition count -> exclusive base
    __shared__ int wtot[SPT / 64];   // per-wave scan totals
    __shared__ int sval[PSCH];
    const int tid = threadIdx.x;
    const int lane = tid & 63;
    const int wv = tid >> 6;
    const int b = blockIdx.x;

    for (int i = tid; i < np; i += SPT) cnt[i] = 0;

    // (A) Fs16 conversion slice — pure global traffic, before first barrier
    {
        const int r0 = b * rows_per;
        const int r1 = min(r0 + rows_per, n_nodes);
        for (int idx = r0 * FEATS + tid; idx < r1 * FEATS; idx += SPT) {
            const float w = rsqrtf(degree[idx >> 6]);
            Fs16[idx] = f2bf(feature[idx] * w);
        }
        if (b == 0) {
            if (tid < FEATS) Fs16[(size_t)n_nodes * FEATS + tid] = 0;  // zero row
            for (int idx = tid; idx < FEATS * FEATS; idx += SPT) {
                const int k = idx >> 6, n = idx & 63;
                WtB[n * FEATS + k] = f2bf(Wm[idx]);     // W^T in bf16
            }
        }
    }
    __syncthreads();                                    // barrier 1

    // (B) pass 1: count + rank. prk64 = src | dl<<17 | p<<23 | r<<34
    const int estart = b * PSCH;
    const int eend = min(estart + PSCH, n_edges);
    const int mb = eend - estart;

    unsigned long long prk[PEPT];
#pragma unroll
    for (int k = 0; k < PEPT; ++k) {
        const int e = estart + tid + k * SPT;
        prk[k] = 0;
        if (e < eend) {
            const int d = dst[e];
            const int p = d >> 6;
            const int r = atomicAdd(&cnt[p], 1);        // LDS atomic (native int)
            prk[k] = (unsigned long long)(src[e] & 0x1FFFF)
                   | ((unsigned long long)(d & 63) << 17)
                   | ((unsigned long long)p << 23)
                   | ((unsigned long long)r << 34);
        }
    }
    __syncthreads();                                    // barrier 2

    // hierarchical exclusive scan of cnt[0..np): 3 partitions per thread
    const int p0 = tid * 3;
    int c0 = 0, c1 = 0, c2 = 0;
    if (p0 + 0 < np) c0 = cnt[p0 + 0];
    if (p0 + 1 < np) c1 = cnt[p0 + 1];
    if (p0 + 2 < np) c2 = cnt[p0 + 2];
    const int s = c0 + c1 + c2;
    int incl = s;
#pragma unroll
    for (int o = 1; o < 64; o <<= 1) {
        const int v = __shfl_up(incl, o);
        if (lane >= o) incl += v;
    }
    if (lane == 63) wtot[wv] = incl;
    __syncthreads();                                    // barrier 3
    int woff = 0;
#pragma unroll
    for (int j = 0; j < SPT / 64; ++j) woff += (j < wv) ? wtot[j] : 0;
    const int tbase = woff + incl - s;
    if (p0 + 0 < np) cnt[p0 + 0] = tbase;
    if (p0 + 1 < np) cnt[p0 + 1] = tbase + c0;
    if (p0 + 2 < np) cnt[p0 + 2] = tbase + c0 + c1;
    __syncthreads();                                    // barrier 4

    // pass 2: place records (no global reads — everything is in prk64)
#pragma unroll
    for (int k = 0; k < PEPT; ++k) {
        const int e = estart + tid + k * SPT;
        if (e < eend) {
            const unsigned long long pr = prk[k];
            const int p = (int)(pr >> 23) & 2047;
            const int r = (int)(pr >> 34);
            sval[cnt[p] + r] = (int)(pr & 0x7FFFFF);    // src | dl<<17
        }
    }
    __syncthreads();                                    // barrier 5

    int* so = slab + estart;
    for (int i = tid; i < mb; i += SPT) so[i] = sval[i];   // coalesced
    unsigned short* ro = runoff + (size_t)b * (np + 1);
    for (int i = tid; i <= np; i += SPT)
        ro[i] = (unsigned short)((i < np) ? cnt[i] : mb);
}

// ---------------------------------------------------------------------------
// K2 gather_apply6: block = partition p. NO fp32 LDS atomics.
//  (a) per-node 8-aligned bucket offsets from degree (wave-0 shuffle scan),
//  (b) prefill ledges with zero-row index, bucket records by node from the
//      sorted slab runs (int LDS atomics only),
//  (c) register accumulation, 8 edges per wave-load: 8 lanes per row, each
//      lane loads uint4 (8 bf16 cols) -> one wave-load = 8 full rows (1KB);
//      one LDS index-read per 8 edges; zero-pad = no tail; 3 shuffles
//      (^8,^16,^32) fold the 8-way partials,
//  (d) MFMA epilogue: bf16 A-tile (stride 72), 8x mfma_16x16x32_bf16,
//      out = swinv[n]*(A@W)+b.
// ---------------------------------------------------------------------------
__global__ __launch_bounds__(256) void gather_apply6(
        const int* __restrict__ slab,
        const unsigned short* __restrict__ runoff,
        const float* __restrict__ degree,
        const unsigned short* __restrict__ Fs16,
        const unsigned short* __restrict__ WtB,
        const float* __restrict__ bias,
        float* __restrict__ out,
        int n_nodes, int np, int nbs) {
    __shared__ __align__(16) int ledges[CAPP];                // 10 KB
    __shared__ __align__(16) unsigned short saggb[PSZ * 72];  // 9.2 KB bf16 A-tile
    __shared__ int boffA[PSZ + 1];
    __shared__ int bcur[PSZ];
    __shared__ float swinv[PSZ];

    const int tid = threadIdx.x;
    const int lane = tid & 63;
    const int wv = tid >> 6;
    const int p = blockIdx.x;
    const int n0 = p * PSZ;
    const int nn = min(PSZ, n_nodes - n0);

    if (tid < PSZ) bcur[tid] = 0;
    if (wv == 0) {   // wave-0: swinv + shuffle scan of 8-padded counts
        const float dg = (lane < nn) ? degree[n0 + lane] : 1.0f;
        swinv[lane] = rsqrtf(dg);
        const int c = (lane < nn) ? ((int)(dg + 0.5f) - 1) : 0;
        const int cp = (c + 7) & ~7;
        int x = cp;
#pragma unroll
        for (int off = 1; off < 64; off <<= 1) {
            const int v = __shfl_up(x, off);
            if (lane >= off) x += v;
        }
        if (lane == 0) boffA[0] = 0;
        boffA[lane + 1] = x;
    }
    __syncthreads();
    const int mpad = boffA[PSZ];
    const uint4* FsU4 = (const uint4*)Fs16;   // 8 uint4 per 128B row

    if (mpad <= CAPP) {
        // (b) prefill pad slots with zero-row index, then bucket
        for (int i = tid; i < mpad; i += 256) ledges[i] = n_nodes;
        __syncthreads();
        for (int rr = tid; rr < nbs; rr += 256) {
            const unsigned short* ro = runoff + (size_t)rr * (np + 1);
            const int st = ro[p];
            const int en = ro[p + 1];
            const int* g = slab + (size_t)rr * PSCH;
            for (int q = st; q < en; ++q) {
                const int rec = g[q];
                const int dl = (rec >> 17) & 63;
                const int pos = boffA[dl] + atomicAdd(&bcur[dl], 1);
                ledges[pos] = rec & 0x1FFFF;
            }
        }
        __syncthreads();

        // (c) 8 edges per wave-load (uint4/lane = 8 bf16 cols, 8 lanes/row)
        const int q8 = lane >> 3;                  // edge-in-group 0..7
        const int c8 = lane & 7;                   // 8 cols per lane
        for (int n = wv; n < PSZ; n += 4) {
            const int st = boffA[n];
            const int en8 = boffA[n + 1];
            float a0 = 0.f, a1 = 0.f, a2 = 0.f, a3 = 0.f;
            float a4 = 0.f, a5 = 0.f, a6 = 0.f, a7 = 0.f;
#pragma unroll 2
            for (int j = st; j < en8; j += 8) {
                const int r0 = ledges[j + q8];
                const uint4 u = FsU4[((size_t)r0 << 3) + c8];
                a0 += bflo(u.x); a1 += bfhi(u.x);
                a2 += bflo(u.y); a3 += bfhi(u.y);
                a4 += bflo(u.z); a5 += bfhi(u.z);
                a6 += bflo(u.w); a7 += bfhi(u.w);
            }
#pragma unroll
            for (int o = 8; o < 64; o <<= 1) {
                a0 += __shfl(a0, lane ^ o);
                a1 += __shfl(a1, lane ^ o);
                a2 += __shfl(a2, lane ^ o);
                a3 += __shfl(a3, lane ^ o);
                a4 += __shfl(a4, lane ^ o);
                a5 += __shfl(a5, lane ^ o);
                a6 += __shfl(a6, lane ^ o);
                a7 += __shfl(a7, lane ^ o);
            }
            if (q8 == 0) {   // lanes 0-7 hold cols c8*8 .. c8*8+7
                uint4 pk;
                pk.x = (unsigned int)f2bf(a0) | ((unsigned int)f2bf(a1) << 16);
                pk.y = (unsigned int)f2bf(a2) | ((unsigned int)f2bf(a3) << 16);
                pk.z = (unsigned int)f2bf(a4) | ((unsigned int)f2bf(a5) << 16);
                pk.w = (unsigned int)f2bf(a6) | ((unsigned int)f2bf(a7) << 16);
                *(uint4*)(saggb + n * 72 + c8 * 8) = pk;   // 144B row stride, 16B aligned
            }
        }
    } else {
        // statistically-unreachable overflow: per-node scan of all runs
        __syncthreads();
        __syncthreads();
        for (int n = wv; n < PSZ; n += 4) {
            float acc = 0.f;
            for (int t = 0; t < nbs; ++t) {
                const unsigned short* ro = runoff + (size_t)t * (np + 1);
                const int gb = t * PSCH;
                const int e0 = ro[p + 1];
                for (int i = ro[p]; i < e0; ++i) {
                    const int rec = slab[gb + i];
                    if (((rec >> 17) & 63) == n) {
                        const unsigned int us =
                            Fs16[((size_t)(rec & 0x1FFFF) << 6) + lane];
                        acc += __uint_as_float(us << 16);
                    }
                }
            }
            saggb[n * 72 + lane] = f2bf(acc);
        }
    }
    __syncthreads();

    // (d) 64x64x64 GEMM: wave wv owns m-tile wv; 4 n-tiles x 2 k-steps = 8 MFMA
    const int col = lane & 15;
    const int quad = lane >> 4;
    floatx4 acc[4] = {};
#pragma unroll
    for (int kt = 0; kt < 2; ++kt) {
        const short8 af = *(const short8*)(saggb + (wv * 16 + col) * 72 + kt * 32 + quad * 8);
#pragma unroll
        for (int nt = 0; nt < 4; ++nt) {
            const short8 bf = *(const short8*)((const short*)WtB + (nt * 16 + col) * FEATS + kt * 32 + quad * 8);
            acc[nt] = __builtin_amdgcn_mfma_f32_16x16x32_bf16(af, bf, acc[nt], 0, 0, 0);
        }
    }
#pragma unroll
    for (int nt = 0; nt < 4; ++nt) {
        const float bv = bias[nt * 16 + col];
#pragma unroll
        for (int r = 0; r < 4; ++r) {
            const int row = wv * 16 + quad * 4 + r;      // D: col=lane&15, row=quad*4+reg
            if (row < nn)
                out[(size_t)(n0 + row) * FEATS + nt * 16 + col] = swinv[row] * acc[nt][r] + bv;
        }
    }
}

static inline size_t align256(size_t x) { return (x + 255) & ~(size_t)255; }

extern "C" void kernel_launch(void* const* d_in, const int* in_sizes, int n_in,
                              void* d_out, int out_size, void* d_ws, size_t ws_size,
                              hipStream_t stream) {
    const float* feature = (const float*)d_in[0];
    const float* degree  = (const float*)d_in[1];
    const int*   src     = (const int*)d_in[2];
    const int*   dst     = (const int*)d_in[3];
    const float* Wm      = (const float*)d_in[4];
    const float* bias    = (const float*)d_in[5];
    float* out = (float*)d_out;

    const int n_nodes = in_sizes[1];
    const int n_edges = in_sizes[2];
    const int np = (n_nodes + PSZ - 1) / PSZ;           // 1172
    const int nbs = (n_edges + PSCH - 1) / PSCH;        // 512
    const int rows_per = (n_nodes + nbs - 1) / nbs;     // 147

    // workspace (~15.7 MB), every byte read is rewritten each launch
    char* ws = (char*)d_ws;
    unsigned short* Fs16 = (unsigned short*)ws; ws += align256(((size_t)n_nodes + 1) * FEATS * 2);
    unsigned short* WtB  = (unsigned short*)ws; ws += align256((size_t)FEATS * FEATS * 2);
    int* slab = (int*)ws;                       ws += align256((size_t)nbs * PSCH * 4);
    unsigned short* runoff = (unsigned short*)ws; ws += align256((size_t)nbs * (np + 1) * 2);

    prep_scatter<<<nbs, SPT, 0, stream>>>(degree, feature, Wm, src, dst,
                                          Fs16, WtB, slab, runoff,
                                          n_nodes, n_edges, np, rows_per);
    gather_apply6<<<np, 256, 0, stream>>>(slab, runoff, degree, Fs16, WtB, bias, out,
                                          n_nodes, np, nbs);
}

// Round 10
// 137.535 us; speedup vs baseline: 1.0414x; 1.0414x over previous
//
#include <hip/hip_runtime.h>

#define FEATS 64
#define PSZ   64            // nodes per partition (= one gather block)
#define MAXP  1280          // >= np = 1172
#define PSCH  1172          // edges per chunk; 1172*1024 >= 1.2M
#define SPT   256           // prep_scatter threads per block
#define PEPT  5             // ceil(PSCH/SPT)
#define NBMAX 1024          // sort blocks = runs per partition
#define CAPP  2560          // padded LDS bucket capacity (mean ~1250, >30 sigma)

typedef __attribute__((ext_vector_type(8))) short short8;   // 8 bf16 = 4 VGPRs
typedef __attribute__((ext_vector_type(4))) float floatx4;  // MFMA accumulator

static __device__ __forceinline__ unsigned short f2bf(float f) {
    const unsigned int u = __float_as_uint(f);
    return (unsigned short)((u + 0x7FFFu + ((u >> 16) & 1u)) >> 16);
}
static __device__ __forceinline__ float bflo(unsigned int u) {
    return __uint_as_float(u << 16);            // low bf16 -> fp32
}
static __device__ __forceinline__ float bfhi(unsigned int u) {
    return __uint_as_float(u & 0xFFFF0000u);    // high bf16 -> fp32
}

// ---------------------------------------------------------------------------
// K1 prep_scatter (fused, 1024 small blocks for phase interleaving):
//  (A) Fs16 = bf16(feature * rsqrt(degree[row])) node-slice; block 0 also
//      writes the zero pad-row and WtB = W^T bf16.
//  (B) partition-sort of the block's 1172-edge chunk in LDS. prk is 64-bit
//      (src|dl|p|r) so pass 2 reads NO global memory. Partition-count scan
//      is hierarchical wave-shuffle (4 barriers total). ZERO global atomics.
//  ~10 KB LDS/block -> 4 blocks/CU resident.
// ---------------------------------------------------------------------------
__global__ __launch_bounds__(SPT) void prep_scatter(
        const float* __restrict__ degree,
        const float* __restrict__ feature,
        const float* __restrict__ Wm,
        const int* __restrict__ src,
        const int* __restrict__ dst,
        unsigned short* __restrict__ Fs16,
        unsigned short* __restrict__ WtB,
        int* __restrict__ slab,
        unsigned short* __restrict__ runoff,
        int n_nodes, int n_edges, int np, int rows_per) {
    __shared__ int cnt[MAXP];        // per-partition count -> exclusive base
    __shared__ int wtot[SPT / 64];   // per-wave scan totals
    __shared__ int sval[PSCH];
    const int tid = threadIdx.x;
    const int lane = tid & 63;
    const int wv = tid >> 6;
    const int b = blockIdx.x;

    for (int i = tid; i < np; i += SPT) cnt[i] = 0;

    // (A) Fs16 conversion slice — pure global traffic, before first barrier
    {
        const int r0 = b * rows_per;
        const int r1 = min(r0 + rows_per, n_nodes);
        for (int idx = r0 * FEATS + tid; idx < r1 * FEATS; idx += SPT) {
            const float w = rsqrtf(degree[idx >> 6]);
            Fs16[idx] = f2bf(feature[idx] * w);
        }
        if (b == 0) {
            if (tid < FEATS) Fs16[(size_t)n_nodes * FEATS + tid] = 0;  // zero row
            for (int idx = tid; idx < FEATS * FEATS; idx += SPT) {
                const int k = idx >> 6, n = idx & 63;
                WtB[n * FEATS + k] = f2bf(Wm[idx]);     // W^T in bf16
            }
        }
    }
    __syncthreads();                                    // barrier 1

    // (B) pass 1: count + rank. prk64 = src | dl<<17 | p<<23 | r<<34
    const int estart = b * PSCH;
    const int eend = min(estart + PSCH, n_edges);
    const int mb = eend - estart;

    unsigned long long prk[PEPT];
#pragma unroll
    for (int k = 0; k < PEPT; ++k) {
        const int e = estart + tid + k * SPT;
        prk[k] = 0;
        if (e < eend) {
            const int d = dst[e];
            const int p = d >> 6;
            const int r = atomicAdd(&cnt[p], 1);        // LDS atomic (native int)
            prk[k] = (unsigned long long)(src[e] & 0x1FFFF)
                   | ((unsigned long long)(d & 63) << 17)
                   | ((unsigned long long)p << 23)
                   | ((unsigned long long)r << 34);
        }
    }
    __syncthreads();                                    // barrier 2

    // hierarchical exclusive scan of cnt[0..np): 5 partitions per thread
    const int p0 = tid * 5;
    int c[5];
    int my[5];
    int s = 0;
#pragma unroll
    for (int j = 0; j < 5; ++j) {
        const int p = p0 + j;
        c[j] = (p < np) ? cnt[p] : 0;
        my[j] = s;
        s += c[j];
    }
    int incl = s;
#pragma unroll
    for (int o = 1; o < 64; o <<= 1) {
        const int v = __shfl_up(incl, o);
        if (lane >= o) incl += v;
    }
    if (lane == 63) wtot[wv] = incl;
    __syncthreads();                                    // barrier 3
    int woff = 0;
#pragma unroll
    for (int j = 0; j < SPT / 64; ++j) woff += (j < wv) ? wtot[j] : 0;
    const int tbase = woff + incl - s;
#pragma unroll
    for (int j = 0; j < 5; ++j) {
        const int p = p0 + j;
        if (p < np) cnt[p] = tbase + my[j];
    }
    __syncthreads();                                    // barrier 4

    // pass 2: place records (no global reads — everything is in prk64)
#pragma unroll
    for (int k = 0; k < PEPT; ++k) {
        const int e = estart + tid + k * SPT;
        if (e < eend) {
            const unsigned long long pr = prk[k];
            const int p = (int)(pr >> 23) & 2047;
            const int r = (int)(pr >> 34);
            sval[cnt[p] + r] = (int)(pr & 0x7FFFFF);    // src | dl<<17
        }
    }
    __syncthreads();                                    // barrier 5

    int* so = slab + estart;
    for (int i = tid; i < mb; i += SPT) so[i] = sval[i];   // coalesced
    unsigned short* ro = runoff + (size_t)b * (np + 1);
    for (int i = tid; i <= np; i += SPT)
        ro[i] = (unsigned short)((i < np) ? cnt[i] : mb);
}

// ---------------------------------------------------------------------------
// K2 gather_apply5 (R8 structure, proven fastest): block = partition p.
//  (a) per-node 8-aligned bucket offsets from degree (wave-0 shuffle scan),
//  (b) prefill ledges with zero-row index (pad slots harmless), bucket
//      records by node from the sorted slab runs (int LDS atomics only),
//  (c) register accumulation, 4 edges per wave-load: quarter q4 = lane>>4
//      takes edge j+q4, each lane loads uint2 (4 bf16 cols); zero-pad = no
//      tail; two shuffles (lane^16, lane^32) fold quarter partials,
//  (d) MFMA epilogue: bf16 A-tile (stride 72), 8x mfma_16x16x32_bf16,
//      out = swinv[n]*(A@W)+b.
// ---------------------------------------------------------------------------
__global__ __launch_bounds__(256) void gather_apply5(
        const int* __restrict__ slab,
        const unsigned short* __restrict__ runoff,
        const float* __restrict__ degree,
        const unsigned short* __restrict__ Fs16,
        const unsigned short* __restrict__ WtB,
        const float* __restrict__ bias,
        float* __restrict__ out,
        int n_nodes, int np, int nbs) {
    __shared__ __align__(16) int ledges[CAPP];                // 10 KB
    __shared__ __align__(16) unsigned short saggb[PSZ * 72];  // 9.2 KB bf16 A-tile
    __shared__ int boffA[PSZ + 1];
    __shared__ int bcur[PSZ];
    __shared__ float swinv[PSZ];

    const int tid = threadIdx.x;
    const int lane = tid & 63;
    const int wv = tid >> 6;
    const int p = blockIdx.x;
    const int n0 = p * PSZ;
    const int nn = min(PSZ, n_nodes - n0);

    if (tid < PSZ) bcur[tid] = 0;
    if (wv == 0) {   // wave-0: swinv + shuffle scan of 8-padded counts
        const float dg = (lane < nn) ? degree[n0 + lane] : 1.0f;
        swinv[lane] = rsqrtf(dg);
        const int c = (lane < nn) ? ((int)(dg + 0.5f) - 1) : 0;
        const int cp = (c + 7) & ~7;
        int x = cp;
#pragma unroll
        for (int off = 1; off < 64; off <<= 1) {
            const int v = __shfl_up(x, off);
            if (lane >= off) x += v;
        }
        if (lane == 0) boffA[0] = 0;
        boffA[lane + 1] = x;
    }
    __syncthreads();
    const int mpad = boffA[PSZ];
    const uint2* FsU2 = (const uint2*)Fs16;   // 16 uint2 per 128B row

    if (mpad <= CAPP) {
        // (b) prefill pad slots with zero-row index, then bucket
        for (int i = tid; i < mpad; i += 256) ledges[i] = n_nodes;
        __syncthreads();
        for (int rr = tid; rr < nbs; rr += 256) {
            const unsigned short* ro = runoff + (size_t)rr * (np + 1);
            const int st = ro[p];
            const int en = ro[p + 1];
            const int* g = slab + (size_t)rr * PSCH;
            for (int q = st; q < en; ++q) {
                const int rec = g[q];
                const int dl = (rec >> 17) & 63;
                const int pos = boffA[dl] + atomicAdd(&bcur[dl], 1);
                ledges[pos] = rec & 0x1FFFF;
            }
        }
        __syncthreads();

        // (c) 4 edges per wave-load (uint2/lane), 2 loads per 8-edge step
        const int q4 = lane >> 4;                  // quarter: edge within group
        const int c16 = lane & 15;                 // 4 cols per lane
        for (int n = wv; n < PSZ; n += 4) {
            const int st = boffA[n];
            const int en8 = boffA[n + 1];
            float a0 = 0.f, a1 = 0.f, a2 = 0.f, a3 = 0.f;
            float c0 = 0.f, c1 = 0.f, c2 = 0.f, c3 = 0.f;
#pragma unroll 2
            for (int j = st; j < en8; j += 8) {
                const int r0 = ledges[j + q4];
                const int r1 = ledges[j + 4 + q4];
                const uint2 u0 = FsU2[((size_t)r0 << 4) + c16];
                const uint2 u1 = FsU2[((size_t)r1 << 4) + c16];
                a0 += bflo(u0.x); a1 += bfhi(u0.x);
                a2 += bflo(u0.y); a3 += bfhi(u0.y);
                c0 += bflo(u1.x); c1 += bfhi(u1.x);
                c2 += bflo(u1.y); c3 += bfhi(u1.y);
            }
            float v0 = a0 + c0, v1 = a1 + c1, v2 = a2 + c2, v3 = a3 + c3;
            v0 += __shfl(v0, lane ^ 16); v0 += __shfl(v0, lane ^ 32);
            v1 += __shfl(v1, lane ^ 16); v1 += __shfl(v1, lane ^ 32);
            v2 += __shfl(v2, lane ^ 16); v2 += __shfl(v2, lane ^ 32);
            v3 += __shfl(v3, lane ^ 16); v3 += __shfl(v3, lane ^ 32);
            if (q4 == 0) {   // lanes 0-15 hold cols c16*4 .. c16*4+3
                const unsigned int pk0 =
                    (unsigned int)f2bf(v0) | ((unsigned int)f2bf(v1) << 16);
                const unsigned int pk1 =
                    (unsigned int)f2bf(v2) | ((unsigned int)f2bf(v3) << 16);
                uint2* dp = (uint2*)(saggb + n * 72 + c16 * 4);
                *dp = make_uint2(pk0, pk1);
            }
        }
    } else {
        // statistically-unreachable overflow: per-node scan of all runs
        __syncthreads();
        __syncthreads();
        for (int n = wv; n < PSZ; n += 4) {
            float acc = 0.f;
            for (int t = 0; t < nbs; ++t) {
                const unsigned short* ro = runoff + (size_t)t * (np + 1);
                const int gb = t * PSCH;
                const int e0 = ro[p + 1];
                for (int i = ro[p]; i < e0; ++i) {
                    const int rec = slab[gb + i];
                    if (((rec >> 17) & 63) == n) {
                        const unsigned int us =
                            Fs16[((size_t)(rec & 0x1FFFF) << 6) + lane];
                        acc += __uint_as_float(us << 16);
                    }
                }
            }
            saggb[n * 72 + lane] = f2bf(acc);
        }
    }
    __syncthreads();

    // (d) 64x64x64 GEMM: wave wv owns m-tile wv; 4 n-tiles x 2 k-steps = 8 MFMA
    const int col = lane & 15;
    const int quad = lane >> 4;
    floatx4 acc[4] = {};
#pragma unroll
    for (int kt = 0; kt < 2; ++kt) {
        const short8 af = *(const short8*)(saggb + (wv * 16 + col) * 72 + kt * 32 + quad * 8);
#pragma unroll
        for (int nt = 0; nt < 4; ++nt) {
            const short8 bf = *(const short8*)((const short*)WtB + (nt * 16 + col) * FEATS + kt * 32 + quad * 8);
            acc[nt] = __builtin_amdgcn_mfma_f32_16x16x32_bf16(af, bf, acc[nt], 0, 0, 0);
        }
    }
#pragma unroll
    for (int nt = 0; nt < 4; ++nt) {
        const float bv = bias[nt * 16 + col];
#pragma unroll
        for (int r = 0; r < 4; ++r) {
            const int row = wv * 16 + quad * 4 + r;      // D: col=lane&15, row=quad*4+reg
            if (row < nn)
                out[(size_t)(n0 + row) * FEATS + nt * 16 + col] = swinv[row] * acc[nt][r] + bv;
        }
    }
}

static inline size_t align256(size_t x) { return (x + 255) & ~(size_t)255; }

extern "C" void kernel_launch(void* const* d_in, const int* in_sizes, int n_in,
                              void* d_out, int out_size, void* d_ws, size_t ws_size,
                              hipStream_t stream) {
    const float* feature = (const float*)d_in[0];
    const float* degree  = (const float*)d_in[1];
    const int*   src     = (const int*)d_in[2];
    const int*   dst     = (const int*)d_in[3];
    const float* Wm      = (const float*)d_in[4];
    const float* bias    = (const float*)d_in[5];
    float* out = (float*)d_out;

    const int n_nodes = in_sizes[1];
    const int n_edges = in_sizes[2];
    const int np = (n_nodes + PSZ - 1) / PSZ;           // 1172
    const int nbs = (n_edges + PSCH - 1) / PSCH;        // 1024
    const int rows_per = (n_nodes + nbs - 1) / nbs;     // 74

    // workspace (~17 MB), every byte read is rewritten each launch
    char* ws = (char*)d_ws;
    unsigned short* Fs16 = (unsigned short*)ws; ws += align256(((size_t)n_nodes + 1) * FEATS * 2);
    unsigned short* WtB  = (unsigned short*)ws; ws += align256((size_t)FEATS * FEATS * 2);
    int* slab = (int*)ws;                       ws += align256((size_t)nbs * PSCH * 4);
    unsigned short* runoff = (unsigned short*)ws; ws += align256((size_t)nbs * (np + 1) * 2);

    prep_scatter<<<nbs, SPT, 0, stream>>>(degree, feature, Wm, src, dst,
                                          Fs16, WtB, slab, runoff,
                                          n_nodes, n_edges, np, rows_per);
    gather_apply5<<<np, 256, 0, stream>>>(slab, runoff, degree, Fs16, WtB, bias, out,
                                          n_nodes, np, nbs);
}

// Round 11
// 136.346 us; speedup vs baseline: 1.0505x; 1.0087x over previous
//
#include <hip/hip_runtime.h>

#define FEATS 64
#define PSZ   64            // nodes per partition (= one gather block)
#define MAXP  1536          // 512 threads * 3 partitions >= 1172
#define PSCH  2344          // edges per chunk; 2344*512 >= 1.2M
#define SPT   512           // prep_scatter threads per block
#define PEPT  5             // ceil(PSCH/SPT)
#define NBMAX 512           // sort blocks = runs per partition
#define CAPP  2560          // padded LDS bucket capacity (16-aligned buckets)

typedef __attribute__((ext_vector_type(8))) short short8;   // 8 bf16 = 4 VGPRs
typedef __attribute__((ext_vector_type(4))) float floatx4;  // MFMA accumulator

static __device__ __forceinline__ unsigned short f2bf(float f) {
    const unsigned int u = __float_as_uint(f);
    return (unsigned short)((u + 0x7FFFu + ((u >> 16) & 1u)) >> 16);
}
static __device__ __forceinline__ float bflo(unsigned int u) {
    return __uint_as_float(u << 16);            // low bf16 -> fp32
}
static __device__ __forceinline__ float bfhi(unsigned int u) {
    return __uint_as_float(u & 0xFFFF0000u);    // high bf16 -> fp32
}

// ---------------------------------------------------------------------------
// K1 prep_scatter (fused, 512x512 — best-measured config):
//  (A) Fs16 = bf16(feature * rsqrt(degree[row])) node-slice; block 0 also
//      writes the zero pad-row and WtB = W^T bf16.
//  (B) partition-sort of the block's 2344-edge chunk in LDS. prk is 64-bit
//      (src|dl|p|r) so pass 2 reads NO global memory. Hierarchical
//      wave-shuffle scan. Run table packed u32 = start | len<<16, written
//      right after the scan (overlaps pass 2). ZERO global atomics.
// ---------------------------------------------------------------------------
__global__ __launch_bounds__(SPT) void prep_scatter(
        const float* __restrict__ degree,
        const float* __restrict__ feature,
        const float* __restrict__ Wm,
        const int* __restrict__ src,
        const int* __restrict__ dst,
        unsigned short* __restrict__ Fs16,
        unsigned short* __restrict__ WtB,
        int* __restrict__ slab,
        unsigned int* __restrict__ runoff,
        int n_nodes, int n_edges, int np, int rows_per) {
    __shared__ int cnt[MAXP];        // per-partition count -> exclusive base
    __shared__ int wtot[SPT / 64];   // per-wave scan totals
    __shared__ int sval[PSCH];
    const int tid = threadIdx.x;
    const int lane = tid & 63;
    const int wv = tid >> 6;
    const int b = blockIdx.x;

    for (int i = tid; i < np; i += SPT) cnt[i] = 0;

    // (A) Fs16 conversion slice — pure global traffic, before first barrier
    {
        const int r0 = b * rows_per;
        const int r1 = min(r0 + rows_per, n_nodes);
        for (int idx = r0 * FEATS + tid; idx < r1 * FEATS; idx += SPT) {
            const float w = rsqrtf(degree[idx >> 6]);
            Fs16[idx] = f2bf(feature[idx] * w);
        }
        if (b == 0) {
            if (tid < FEATS) Fs16[(size_t)n_nodes * FEATS + tid] = 0;  // zero row
            for (int idx = tid; idx < FEATS * FEATS; idx += SPT) {
                const int k = idx >> 6, n = idx & 63;
                WtB[n * FEATS + k] = f2bf(Wm[idx]);     // W^T in bf16
            }
        }
    }
    __syncthreads();                                    // barrier 1

    // (B) pass 1: count + rank. prk64 = src | dl<<17 | p<<23 | r<<34
    const int estart = b * PSCH;
    const int eend = min(estart + PSCH, n_edges);
    const int mb = eend - estart;

    unsigned long long prk[PEPT];
#pragma unroll
    for (int k = 0; k < PEPT; ++k) {
        const int e = estart + tid + k * SPT;
        prk[k] = 0;
        if (e < eend) {
            const int d = dst[e];
            const int p = d >> 6;
            const int r = atomicAdd(&cnt[p], 1);        // LDS atomic (native int)
            prk[k] = (unsigned long long)(src[e] & 0x1FFFF)
                   | ((unsigned long long)(d & 63) << 17)
                   | ((unsigned long long)p << 23)
                   | ((unsigned long long)r << 34);
        }
    }
    __syncthreads();                                    // barrier 2

    // hierarchical exclusive scan of cnt[0..np): 3 partitions per thread
    const int p0 = tid * 3;
    int c0 = 0, c1 = 0, c2 = 0;
    if (p0 + 0 < np) c0 = cnt[p0 + 0];
    if (p0 + 1 < np) c1 = cnt[p0 + 1];
    if (p0 + 2 < np) c2 = cnt[p0 + 2];
    const int s = c0 + c1 + c2;
    int incl = s;
#pragma unroll
    for (int o = 1; o < 64; o <<= 1) {
        const int v = __shfl_up(incl, o);
        if (lane >= o) incl += v;
    }
    if (lane == 63) wtot[wv] = incl;
    __syncthreads();                                    // barrier 3
    int woff = 0;
#pragma unroll
    for (int j = 0; j < SPT / 64; ++j) woff += (j < wv) ? wtot[j] : 0;
    const int tbase = woff + incl - s;
    if (p0 + 0 < np) cnt[p0 + 0] = tbase;
    if (p0 + 1 < np) cnt[p0 + 1] = tbase + c0;
    if (p0 + 2 < np) cnt[p0 + 2] = tbase + c0 + c1;
    __syncthreads();                                    // barrier 4

    // packed run table (depends only on cnt, stable after barrier 4):
    // runoff[b][p] = start | len<<16
    {
        unsigned int* ro = runoff + (size_t)b * np;
        ro[p0 + 0 < np ? 0 : 0] = ro[0];               // no-op touch avoided below
    }
    {
        unsigned int* ro = runoff + (size_t)b * np;
        if (p0 + 0 < np) {
            const int base = tbase;
            const int nxt = (p0 + 1 < np) ? tbase + c0 : mb;
            ro[p0 + 0] = (unsigned int)base | ((unsigned int)(nxt - base) << 16);
        }
        if (p0 + 1 < np) {
            const int base = tbase + c0;
            const int nxt = (p0 + 2 < np) ? tbase + c0 + c1 : mb;
            ro[p0 + 1] = (unsigned int)base | ((unsigned int)(nxt - base) << 16);
        }
        if (p0 + 2 < np) {
            const int base = tbase + c0 + c1;
            const int nxt = cnt[p0 + 3 < np ? p0 + 3 : p0 + 2];  // next thread's tbase
            const int nx2 = (p0 + 3 < np) ? nxt : mb;
            ro[p0 + 2] = (unsigned int)base | ((unsigned int)(nx2 - base) << 16);
        }
    }

    // pass 2: place records (no global reads — everything is in prk64)
#pragma unroll
    for (int k = 0; k < PEPT; ++k) {
        const int e = estart + tid + k * SPT;
        if (e < eend) {
            const unsigned long long pr = prk[k];
            const int p = (int)(pr >> 23) & 2047;
            const int r = (int)(pr >> 34);
            sval[cnt[p] + r] = (int)(pr & 0x7FFFFF);    // src | dl<<17
        }
    }
    __syncthreads();                                    // barrier 5

    int* so = slab + estart;
    for (int i = tid; i < mb; i += SPT) so[i] = sval[i];   // coalesced
}

// ---------------------------------------------------------------------------
// K2 gather_apply7: block = partition p. NO fp32 LDS atomics.
//  (a) per-node 16-aligned bucket offsets from degree (wave-0 shuffle scan),
//  (b) prefill ledges with zero-row index (pad slots harmless), bucket
//      records by node from the sorted slab runs (packed u32 run table,
//      int LDS atomics only),
//  (c) register accumulation, 16 edges/step: 4 uint2 loads + 4 LDS index
//      reads in flight (mean degree 16 -> typically ONE iteration/node);
//      zero-pad = no tail; 2 shuffles (^16,^32) fold quarter partials,
//  (d) MFMA epilogue: bf16 A-tile (stride 72), 8x mfma_16x16x32_bf16,
//      out = swinv[n]*(A@W)+b.
// ---------------------------------------------------------------------------
__global__ __launch_bounds__(256) void gather_apply7(
        const int* __restrict__ slab,
        const unsigned int* __restrict__ runoff,
        const float* __restrict__ degree,
        const unsigned short* __restrict__ Fs16,
        const unsigned short* __restrict__ WtB,
        const float* __restrict__ bias,
        float* __restrict__ out,
        int n_nodes, int np, int nbs) {
    __shared__ __align__(16) int ledges[CAPP];                // 10 KB
    __shared__ __align__(16) unsigned short saggb[PSZ * 72];  // 9.2 KB bf16 A-tile
    __shared__ int boffA[PSZ + 1];
    __shared__ int bcur[PSZ];
    __shared__ float swinv[PSZ];

    const int tid = threadIdx.x;
    const int lane = tid & 63;
    const int wv = tid >> 6;
    const int p = blockIdx.x;
    const int n0 = p * PSZ;
    const int nn = min(PSZ, n_nodes - n0);

    if (tid < PSZ) bcur[tid] = 0;
    if (wv == 0) {   // wave-0: swinv + shuffle scan of 16-padded counts
        const float dg = (lane < nn) ? degree[n0 + lane] : 1.0f;
        swinv[lane] = rsqrtf(dg);
        const int c = (lane < nn) ? ((int)(dg + 0.5f) - 1) : 0;
        const int cp = (c + 15) & ~15;
        int x = cp;
#pragma unroll
        for (int off = 1; off < 64; off <<= 1) {
            const int v = __shfl_up(x, off);
            if (lane >= off) x += v;
        }
        if (lane == 0) boffA[0] = 0;
        boffA[lane + 1] = x;
    }
    __syncthreads();
    const int mpad = boffA[PSZ];
    const uint2* FsU2 = (const uint2*)Fs16;   // 16 uint2 per 128B row

    if (mpad <= CAPP) {
        // (b) prefill pad slots with zero-row index, then bucket
        for (int i = tid; i < mpad; i += 256) ledges[i] = n_nodes;
        __syncthreads();
        for (int rr = tid; rr < nbs; rr += 256) {
            const unsigned int pr = runoff[(size_t)rr * np + p];
            const int st = (int)(pr & 0xFFFFu);
            const int len = (int)(pr >> 16);
            const int* g = slab + (size_t)rr * PSCH + st;
            for (int q = 0; q < len; ++q) {
                const int rec = g[q];
                const int dl = (rec >> 17) & 63;
                const int pos = boffA[dl] + atomicAdd(&bcur[dl], 1);
                ledges[pos] = rec & 0x1FFFF;
            }
        }
        __syncthreads();

        // (c) 16 edges/step: 4 uint2 loads in flight per lane
        const int q4 = lane >> 4;                  // edge-in-group-of-4
        const int c16 = lane & 15;                 // 4 cols per lane
        for (int n = wv; n < PSZ; n += 4) {
            const int st = boffA[n];
            const int en16 = boffA[n + 1];
            float a0 = 0.f, a1 = 0.f, a2 = 0.f, a3 = 0.f;
            float c0 = 0.f, c1 = 0.f, c2 = 0.f, c3 = 0.f;
            for (int j = st; j < en16; j += 16) {
                const int r0 = ledges[j + q4];
                const int r1 = ledges[j + 4 + q4];
                const int r2 = ledges[j + 8 + q4];
                const int r3 = ledges[j + 12 + q4];
                const uint2 u0 = FsU2[((size_t)r0 << 4) + c16];
                const uint2 u1 = FsU2[((size_t)r1 << 4) + c16];
                const uint2 u2 = FsU2[((size_t)r2 << 4) + c16];
                const uint2 u3 = FsU2[((size_t)r3 << 4) + c16];
                a0 += bflo(u0.x); a1 += bfhi(u0.x);
                a2 += bflo(u0.y); a3 += bfhi(u0.y);
                c0 += bflo(u1.x); c1 += bfhi(u1.x);
                c2 += bflo(u1.y); c3 += bfhi(u1.y);
                a0 += bflo(u2.x); a1 += bfhi(u2.x);
                a2 += bflo(u2.y); a3 += bfhi(u2.y);
                c0 += bflo(u3.x); c1 += bfhi(u3.x);
                c2 += bflo(u3.y); c3 += bfhi(u3.y);
            }
            float v0 = a0 + c0, v1 = a1 + c1, v2 = a2 + c2, v3 = a3 + c3;
            v0 += __shfl(v0, lane ^ 16); v0 += __shfl(v0, lane ^ 32);
            v1 += __shfl(v1, lane ^ 16); v1 += __shfl(v1, lane ^ 32);
            v2 += __shfl(v2, lane ^ 16); v2 += __shfl(v2, lane ^ 32);
            v3 += __shfl(v3, lane ^ 16); v3 += __shfl(v3, lane ^ 32);
            if (q4 == 0) {   // lanes 0-15 hold cols c16*4 .. c16*4+3
                const unsigned int pk0 =
                    (unsigned int)f2bf(v0) | ((unsigned int)f2bf(v1) << 16);
                const unsigned int pk1 =
                    (unsigned int)f2bf(v2) | ((unsigned int)f2bf(v3) << 16);
                uint2* dp = (uint2*)(saggb + n * 72 + c16 * 4);
                *dp = make_uint2(pk0, pk1);
            }
        }
    } else {
        // statistically-unreachable overflow: per-node scan of all runs
        __syncthreads();
        __syncthreads();
        for (int n = wv; n < PSZ; n += 4) {
            float acc = 0.f;
            for (int t = 0; t < nbs; ++t) {
                const unsigned int pr = runoff[(size_t)t * np + p];
                const int st = (int)(pr & 0xFFFFu);
                const int len = (int)(pr >> 16);
                const int* g = slab + (size_t)t * PSCH + st;
                for (int i = 0; i < len; ++i) {
                    const int rec = g[i];
                    if (((rec >> 17) & 63) == n) {
                        const unsigned int us =
                            Fs16[((size_t)(rec & 0x1FFFF) << 6) + lane];
                        acc += __uint_as_float(us << 16);
                    }
                }
            }
            saggb[n * 72 + lane] = f2bf(acc);
        }
    }
    __syncthreads();

    // (d) 64x64x64 GEMM: wave wv owns m-tile wv; 4 n-tiles x 2 k-steps = 8 MFMA
    const int col = lane & 15;
    const int quad = lane >> 4;
    floatx4 acc[4] = {};
#pragma unroll
    for (int kt = 0; kt < 2; ++kt) {
        const short8 af = *(const short8*)(saggb + (wv * 16 + col) * 72 + kt * 32 + quad * 8);
#pragma unroll
        for (int nt = 0; nt < 4; ++nt) {
            const short8 bf = *(const short8*)((const short*)WtB + (nt * 16 + col) * FEATS + kt * 32 + quad * 8);
            acc[nt] = __builtin_amdgcn_mfma_f32_16x16x32_bf16(af, bf, acc[nt], 0, 0, 0);
        }
    }
#pragma unroll
    for (int nt = 0; nt < 4; ++nt) {
        const float bv = bias[nt * 16 + col];
#pragma unroll
        for (int r = 0; r < 4; ++r) {
            const int row = wv * 16 + quad * 4 + r;      // D: col=lane&15, row=quad*4+reg
            if (row < nn)
                out[(size_t)(n0 + row) * FEATS + nt * 16 + col] = swinv[row] * acc[nt][r] + bv;
        }
    }
}

static inline size_t align256(size_t x) { return (x + 255) & ~(size_t)255; }

extern "C" void kernel_launch(void* const* d_in, const int* in_sizes, int n_in,
                              void* d_out, int out_size, void* d_ws, size_t ws_size,
                              hipStream_t stream) {
    const float* feature = (const float*)d_in[0];
    const float* degree  = (const float*)d_in[1];
    const int*   src     = (const int*)d_in[2];
    const int*   dst     = (const int*)d_in[3];
    const float* Wm      = (const float*)d_in[4];
    const float* bias    = (const float*)d_in[5];
    float* out = (float*)d_out;

    const int n_nodes = in_sizes[1];
    const int n_edges = in_sizes[2];
    const int np = (n_nodes + PSZ - 1) / PSZ;           // 1172
    const int nbs = (n_edges + PSCH - 1) / PSCH;        // 512
    const int rows_per = (n_nodes + nbs - 1) / nbs;     // 147

    // workspace (~17 MB), every byte read is rewritten each launch
    char* ws = (char*)d_ws;
    unsigned short* Fs16 = (unsigned short*)ws; ws += align256(((size_t)n_nodes + 1) * FEATS * 2);
    unsigned short* WtB  = (unsigned short*)ws; ws += align256((size_t)FEATS * FEATS * 2);
    int* slab = (int*)ws;                       ws += align256((size_t)nbs * PSCH * 4);
    unsigned int* runoff = (unsigned int*)ws;   ws += align256((size_t)nbs * np * 4);

    prep_scatter<<<nbs, SPT, 0, stream>>>(degree, feature, Wm, src, dst,
                                          Fs16, WtB, slab, runoff,
                                          n_nodes, n_edges, np, rows_per);
    gather_apply7<<<np, 256, 0, stream>>>(slab, runoff, degree, Fs16, WtB, bias, out,
                                          n_nodes, np, nbs);
}

// Round 12
// 135.241 us; speedup vs baseline: 1.0591x; 1.0082x over previous
//
#include <hip/hip_runtime.h>

#define FEATS 64
#define PSZ   64            // nodes per partition (= one gather block)
#define MAXP  1280          // >= ceil(75000/64) = 1172
#define PSCH  2344          // edges per chunk; 2344*512 >= 1.2M
#define SPT   512           // prep_scatter threads per block
#define PEPT  5             // ceil(PSCH/SPT)
#define NBMAX 512           // sort blocks = runs per partition
#define CAPP  2560          // padded LDS bucket capacity (mean ~1250, >30 sigma)

typedef __attribute__((ext_vector_type(8))) short short8;   // 8 bf16 = 4 VGPRs
typedef __attribute__((ext_vector_type(4))) float floatx4;  // MFMA accumulator

static __device__ __forceinline__ unsigned short f2bf(float f) {
    const unsigned int u = __float_as_uint(f);
    return (unsigned short)((u + 0x7FFFu + ((u >> 16) & 1u)) >> 16);
}
static __device__ __forceinline__ float bflo(unsigned int u) {
    return __uint_as_float(u << 16);            // low bf16 -> fp32
}
static __device__ __forceinline__ float bfhi(unsigned int u) {
    return __uint_as_float(u & 0xFFFF0000u);    // high bf16 -> fp32
}

// ---------------------------------------------------------------------------
// K1 prep_scatter (fused, 512 threads for 16 waves/CU): each of 512 blocks
//  (A) converts its node-slice of Fs16 = bf16(feature * rsqrt(degree[row]))
//      (block 0 also: zero pad-row at index n_nodes; WtB = W^T bf16),
//  (B) partition-sorts its PSCH-edge chunk in LDS (native int LDS atomics),
//      writes it back coalesced + a u16 run-offset row. ZERO global atomics.
// Record = src | dl<<17 ; prk = p | r<<11 | dl<<23.
// [R8 config — best measured across R7..R11 variants]
// ---------------------------------------------------------------------------
__global__ __launch_bounds__(SPT) void prep_scatter(
        const float* __restrict__ degree,
        const float* __restrict__ feature,
        const float* __restrict__ Wm,
        const int* __restrict__ src,
        const int* __restrict__ dst,
        unsigned short* __restrict__ Fs16,
        unsigned short* __restrict__ WtB,
        int* __restrict__ slab,
        unsigned short* __restrict__ runoff,
        int n_nodes, int n_edges, int np, int rows_per) {
    __shared__ int cnt[MAXP];        // per-partition count, then exclusive loc
    __shared__ int ssum[SPT];
    __shared__ int sval[PSCH];
    const int tid = threadIdx.x;
    const int b = blockIdx.x;

    for (int i = tid; i < np; i += SPT) cnt[i] = 0;

    // (A) Fs16 conversion slice — global-only traffic, overlaps the sort setup
    {
        const int r0 = b * rows_per;
        const int r1 = min(r0 + rows_per, n_nodes);
        for (int idx = r0 * FEATS + tid; idx < r1 * FEATS; idx += SPT) {
            const float w = rsqrtf(degree[idx >> 6]);
            Fs16[idx] = f2bf(feature[idx] * w);
        }
        if (b == 0) {
            if (tid < FEATS) Fs16[(size_t)n_nodes * FEATS + tid] = 0;  // zero row
            for (int idx = tid; idx < FEATS * FEATS; idx += SPT) {
                const int k = idx >> 6, n = idx & 63;
                WtB[n * FEATS + k] = f2bf(Wm[idx]);     // W^T in bf16
            }
        }
    }
    __syncthreads();

    // (B) chunk sort
    const int estart = b * PSCH;
    const int eend = min(estart + PSCH, n_edges);
    const int mb = eend - estart;

    int prk[PEPT];
#pragma unroll
    for (int k = 0; k < PEPT; ++k) {
        const int e = estart + tid + k * SPT;
        prk[k] = 0;
        if (e < eend) {
            const int d = dst[e];
            const int p = d >> 6;                      // 11 bits
            const int r = atomicAdd(&cnt[p], 1);       // LDS atomic (native int)
            prk[k] = p | (r << 11) | ((d & 63) << 23); // r < 2344 (12 bits)
        }
    }
    __syncthreads();

    // block-wide exclusive scan of cnt[0..np): 3 partitions per thread
    int my[3];
    int psum = 0;
    const int p0 = tid * 3;
#pragma unroll
    for (int j = 0; j < 3; ++j) {
        const int p = p0 + j;
        my[j] = psum;
        if (p < np) psum += cnt[p];
    }
    ssum[tid] = psum;
    __syncthreads();
#pragma unroll
    for (int o = 1; o < SPT; o <<= 1) {
        const int v = (tid >= o) ? ssum[tid - o] : 0;
        __syncthreads();
        ssum[tid] += v;
        __syncthreads();
    }
    const int tbase = ssum[tid] - psum;
#pragma unroll
    for (int j = 0; j < 3; ++j) {
        const int p = p0 + j;
        if (p < np) cnt[p] = tbase + my[j];            // cnt becomes loc
    }
    __syncthreads();

#pragma unroll
    for (int k = 0; k < PEPT; ++k) {
        const int e = estart + tid + k * SPT;
        if (e < eend) {
            const int pr = prk[k];
            const int p = pr & 2047;
            const int r = (pr >> 11) & 4095;
            const int dl = (pr >> 23) & 63;
            sval[cnt[p] + r] = (src[e] & 0x1FFFF) | (dl << 17);
        }
    }
    __syncthreads();

    int* so = slab + estart;
    for (int i = tid; i < mb; i += SPT) so[i] = sval[i];   // coalesced
    unsigned short* ro = runoff + (size_t)b * (np + 1);
    for (int i = tid; i <= np; i += SPT)
        ro[i] = (unsigned short)((i < np) ? cnt[i] : mb);
}

// ---------------------------------------------------------------------------
// K2 gather_apply5: block = partition p. NO fp32 LDS atomics.
//  (a) per-node 8-aligned bucket offsets from degree (wave-0 shuffle scan),
//  (b) prefill ledges with zero-row index (pad slots harmless), bucket
//      records by node from the sorted slab runs (int LDS atomics only),
//  (c) register accumulation, 4 edges per wave-load: quarter q4 = lane>>4
//      takes edge j+q4, each lane loads uint2 (4 bf16 cols); zero-pad = no
//      tail; two shuffles (lane^16, lane^32) fold quarter partials,
//  (d) MFMA epilogue: bf16 A-tile (stride 72), 8x mfma_16x16x32_bf16,
//      out = swinv[n]*(A@W)+b.
// [R8 config — best measured; 8-lane/row (R9) and 16-edge-step (R11) both
//  regressed: reduction-tree and issue-width tradeoffs lose at mean deg 16]
// ---------------------------------------------------------------------------
__global__ __launch_bounds__(256) void gather_apply5(
        const int* __restrict__ slab,
        const unsigned short* __restrict__ runoff,
        const float* __restrict__ degree,
        const unsigned short* __restrict__ Fs16,
        const unsigned short* __restrict__ WtB,
        const float* __restrict__ bias,
        float* __restrict__ out,
        int n_nodes, int np, int nbs) {
    __shared__ __align__(16) int ledges[CAPP];                // 10 KB
    __shared__ __align__(16) unsigned short saggb[PSZ * 72];  // 9.2 KB bf16 A-tile
    __shared__ int boffA[PSZ + 1];
    __shared__ int bcur[PSZ];
    __shared__ float swinv[PSZ];

    const int tid = threadIdx.x;
    const int lane = tid & 63;
    const int wv = tid >> 6;
    const int p = blockIdx.x;
    const int n0 = p * PSZ;
    const int nn = min(PSZ, n_nodes - n0);

    if (tid < PSZ) bcur[tid] = 0;
    if (wv == 0) {   // wave-0: swinv + shuffle scan of 8-padded counts
        const float dg = (lane < nn) ? degree[n0 + lane] : 1.0f;
        swinv[lane] = rsqrtf(dg);
        const int c = (lane < nn) ? ((int)(dg + 0.5f) - 1) : 0;
        const int cp = (c + 7) & ~7;
        int x = cp;
#pragma unroll
        for (int off = 1; off < 64; off <<= 1) {
            const int v = __shfl_up(x, off);
            if (lane >= off) x += v;
        }
        if (lane == 0) boffA[0] = 0;
        boffA[lane + 1] = x;
    }
    __syncthreads();
    const int mpad = boffA[PSZ];
    const uint2* FsU2 = (const uint2*)Fs16;   // 16 uint2 per 128B row

    if (mpad <= CAPP) {
        // (b) prefill pad slots with zero-row index, then bucket
        for (int i = tid; i < mpad; i += 256) ledges[i] = n_nodes;
        __syncthreads();
        for (int rr = tid; rr < nbs; rr += 256) {
            const unsigned short* ro = runoff + (size_t)rr * (np + 1);
            const int st = ro[p];
            const int en = ro[p + 1];
            const int* g = slab + (size_t)rr * PSCH;
            for (int q = st; q < en; ++q) {
                const int rec = g[q];
                const int dl = (rec >> 17) & 63;
                const int pos = boffA[dl] + atomicAdd(&bcur[dl], 1);
                ledges[pos] = rec & 0x1FFFF;
            }
        }
        __syncthreads();

        // (c) 4 edges per wave-load (uint2/lane), 2 loads per 8-edge step
        const int q4 = lane >> 4;                  // quarter: edge within group
        const int c16 = lane & 15;                 // 4 cols per lane
        for (int n = wv; n < PSZ; n += 4) {
            const int st = boffA[n];
            const int en8 = boffA[n + 1];
            float a0 = 0.f, a1 = 0.f, a2 = 0.f, a3 = 0.f;
            float c0 = 0.f, c1 = 0.f, c2 = 0.f, c3 = 0.f;
#pragma unroll 2
            for (int j = st; j < en8; j += 8) {
                const int r0 = ledges[j + q4];
                const int r1 = ledges[j + 4 + q4];
                const uint2 u0 = FsU2[((size_t)r0 << 4) + c16];
                const uint2 u1 = FsU2[((size_t)r1 << 4) + c16];
                a0 += bflo(u0.x); a1 += bfhi(u0.x);
                a2 += bflo(u0.y); a3 += bfhi(u0.y);
                c0 += bflo(u1.x); c1 += bfhi(u1.x);
                c2 += bflo(u1.y); c3 += bfhi(u1.y);
            }
            float v0 = a0 + c0, v1 = a1 + c1, v2 = a2 + c2, v3 = a3 + c3;
            v0 += __shfl(v0, lane ^ 16); v0 += __shfl(v0, lane ^ 32);
            v1 += __shfl(v1, lane ^ 16); v1 += __shfl(v1, lane ^ 32);
            v2 += __shfl(v2, lane ^ 16); v2 += __shfl(v2, lane ^ 32);
            v3 += __shfl(v3, lane ^ 16); v3 += __shfl(v3, lane ^ 32);
            if (q4 == 0) {   // lanes 0-15 hold cols c16*4 .. c16*4+3
                const unsigned int pk0 =
                    (unsigned int)f2bf(v0) | ((unsigned int)f2bf(v1) << 16);
                const unsigned int pk1 =
                    (unsigned int)f2bf(v2) | ((unsigned int)f2bf(v3) << 16);
                uint2* dp = (uint2*)(saggb + n * 72 + c16 * 4);
                *dp = make_uint2(pk0, pk1);
            }
        }
    } else {
        // statistically-unreachable overflow: per-node scan of all runs
        __syncthreads();
        __syncthreads();
        for (int n = wv; n < PSZ; n += 4) {
            float acc = 0.f;
            for (int t = 0; t < nbs; ++t) {
                const unsigned short* ro = runoff + (size_t)t * (np + 1);
                const int gb = t * PSCH;
                const int e0 = ro[p + 1];
                for (int i = ro[p]; i < e0; ++i) {
                    const int rec = slab[gb + i];
                    if (((rec >> 17) & 63) == n) {
                        const unsigned int us =
                            Fs16[((size_t)(rec & 0x1FFFF) << 6) + lane];
                        acc += __uint_as_float(us << 16);
                    }
                }
            }
            saggb[n * 72 + lane] = f2bf(acc);
        }
    }
    __syncthreads();

    // (d) 64x64x64 GEMM: wave wv owns m-tile wv; 4 n-tiles x 2 k-steps = 8 MFMA
    const int col = lane & 15;
    const int quad = lane >> 4;
    floatx4 acc[4] = {};
#pragma unroll
    for (int kt = 0; kt < 2; ++kt) {
        const short8 af = *(const short8*)(saggb + (wv * 16 + col) * 72 + kt * 32 + quad * 8);
#pragma unroll
        for (int nt = 0; nt < 4; ++nt) {
            const short8 bf = *(const short8*)((const short*)WtB + (nt * 16 + col) * FEATS + kt * 32 + quad * 8);
            acc[nt] = __builtin_amdgcn_mfma_f32_16x16x32_bf16(af, bf, acc[nt], 0, 0, 0);
        }
    }
#pragma unroll
    for (int nt = 0; nt < 4; ++nt) {
        const float bv = bias[nt * 16 + col];
#pragma unroll
        for (int r = 0; r < 4; ++r) {
            const int row = wv * 16 + quad * 4 + r;      // D: col=lane&15, row=quad*4+reg
            if (row < nn)
                out[(size_t)(n0 + row) * FEATS + nt * 16 + col] = swinv[row] * acc[nt][r] + bv;
        }
    }
}

static inline size_t align256(size_t x) { return (x + 255) & ~(size_t)255; }

extern "C" void kernel_launch(void* const* d_in, const int* in_sizes, int n_in,
                              void* d_out, int out_size, void* d_ws, size_t ws_size,
                              hipStream_t stream) {
    const float* feature = (const float*)d_in[0];
    const float* degree  = (const float*)d_in[1];
    const int*   src     = (const int*)d_in[2];
    const int*   dst     = (const int*)d_in[3];
    const float* Wm      = (const float*)d_in[4];
    const float* bias    = (const float*)d_in[5];
    float* out = (float*)d_out;

    const int n_nodes = in_sizes[1];
    const int n_edges = in_sizes[2];
    const int np = (n_nodes + PSZ - 1) / PSZ;           // 1172
    const int nbs = (n_edges + PSCH - 1) / PSCH;        // 512
    const int rows_per = (n_nodes + nbs - 1) / nbs;     // 147

    // workspace (~15.7 MB), every byte read is rewritten each launch
    char* ws = (char*)d_ws;
    unsigned short* Fs16 = (unsigned short*)ws; ws += align256(((size_t)n_nodes + 1) * FEATS * 2);
    unsigned short* WtB  = (unsigned short*)ws; ws += align256((size_t)FEATS * FEATS * 2);
    int* slab = (int*)ws;                       ws += align256((size_t)nbs * PSCH * 4);
    unsigned short* runoff = (unsigned short*)ws; ws += align256((size_t)nbs * (np + 1) * 2);

    prep_scatter<<<nbs, SPT, 0, stream>>>(degree, feature, Wm, src, dst,
                                          Fs16, WtB, slab, runoff,
                                          n_nodes, n_edges, np, rows_per);
    gather_apply5<<<np, 256, 0, stream>>>(slab, runoff, degree, Fs16, WtB, bias, out,
                                          n_nodes, np, nbs);
}